// Round 11
// baseline (3735.737 us; speedup 1.0000x reference)
//
#include <hip/hip_runtime.h>

#define B 8
#define N 8192
#define S 2048
#define K 32
#define TPB 512           // all blocks: 8 waves
#define PPT (N / TPB)     // 16 contiguous points per FPS thread
#define NPAIR (PPT / 2)   // 8 packed pairs
#define CHUNK_STEP 128    // FPS publish cadence
#define WPB 31            // worker blocks per batch
#define WVB (WPB * 8)     // 248 KNN waves per batch (stride)

typedef float v2f __attribute__((ext_vector_type(2)));

// Exact (no-FMA, left-to-right) squared distance to match numpy fp32:
// ((dx*dx + dy*dy) + dz*dz). FPS argmax is a chaotic recurrence; any ulp
// difference diverges the center sequence. Verified absmax==0 (R1-R10).
__device__ __forceinline__ float sqdist3(float ax, float ay, float az,
                                         float bx, float by, float bz) {
    float dx = ax - bx, dy = ay - by, dz = az - bz;
    return __fadd_rn(__fadd_rn(__fmul_rn(dx, dx), __fmul_rn(dy, dy)),
                     __fmul_rn(dz, dz));
}

template <int CTRL>
__device__ __forceinline__ float dpp_fmax(float v) {
    const int iv = __float_as_int(v);
    const int sh = __builtin_amdgcn_update_dpp(iv, iv, CTRL, 0xF, 0xF, false);
    return fmaxf(v, __int_as_float(sh));
}
__device__ __forceinline__ float wave_fmax_dpp(float v) {
    v = dpp_fmax<0x111>(v);  // row_shr:1
    v = dpp_fmax<0x112>(v);  // row_shr:2
    v = dpp_fmax<0x114>(v);  // row_shr:4
    v = dpp_fmax<0x118>(v);  // row_shr:8
    v = dpp_fmax<0x142>(v);  // row_bcast:15
    v = dpp_fmax<0x143>(v);  // row_bcast:31 -> lane 63 = wave max
    return __int_as_float(__builtin_amdgcn_readlane(__float_as_int(v), 63));
}

// ---------------------------------------------------------------------------
// Fused producer-consumer (R9-verified structure), 256 blocks x 512 threads.
//  - blocks 0..7: FPS producer, R9 scalar structure. R11: ONLY the
//    sub/mul/add distance chain is packed (v_pk_add_f32/v_pk_mul_f32 exist
//    on gfx950; v_pk_min/max_f32 do NOT -- R10 regressed by keeping min/max
//    state vectorized, forcing repack churn). X/Y/Z are v2f constants
//    (packed once at load); d's halves are consumed via free subregister
//    extracts; md[] stays scalar so min/max never touch a vector.
//  - blocks 8..255: strided KNN workers (R9-verified, untouched).
// Tie-break invariants: FPS (max dist, min gid); KNN (d, idx) lexicographic.
// ---------------------------------------------------------------------------
__global__ __launch_bounds__(TPB, 2) void fused_kernel(
    const float* __restrict__ xyz, float* __restrict__ out,
    float* __restrict__ centers, unsigned* __restrict__ progress) {
#pragma clang fp contract(off)
    const int blk = blockIdx.x;
    const int t = threadIdx.x;
    const int lane = t & 63;

    if (blk < B) {
        // =================== FPS producer ===================
        const int b = blk;
        const float* xb = xyz + (size_t)b * N * 3;
        float* cb = centers + (size_t)b * S * 3;
        const int wid = t >> 6;

        // load 16 contiguous points (48 floats = 12 float4); X[j] packs
        // (x_{2j}, x_{2j+1}) etc.; md scalar.
        v2f X[NPAIR], Y[NPAIR], Z[NPAIR];
        float md[PPT];
        {
            float raw[3 * PPT];
            const float4* src = (const float4*)(xb + 3 * PPT * t);
#pragma unroll
            for (int i = 0; i < 3 * PPT / 4; ++i) {
                const float4 v = src[i];
                raw[4 * i + 0] = v.x; raw[4 * i + 1] = v.y;
                raw[4 * i + 2] = v.z; raw[4 * i + 3] = v.w;
            }
#pragma unroll
            for (int j = 0; j < NPAIR; ++j) {
                X[j] = (v2f){raw[6 * j + 0], raw[6 * j + 3]};
                Y[j] = (v2f){raw[6 * j + 1], raw[6 * j + 4]};
                Z[j] = (v2f){raw[6 * j + 2], raw[6 * j + 5]};
            }
#pragma unroll
            for (int i = 0; i < PPT; ++i) md[i] = INFINITY;
        }

        __shared__ float4 pub[2][8];       // per-wave {wmax,x,y,z}, dbuf
        __shared__ float cent[S * 3];      // centers staged in LDS (24 KB)

        float px = xb[0], py = xb[1], pz = xb[2];   // step 0: point 0
        if (t == 0) { cent[0] = px; cent[1] = py; cent[2] = pz; }

        for (int s = 1; s < S; ++s) {
            // --- packed arithmetic, scalar min/max (no repack anywhere):
            //     d = (dx*dx + dy*dy) + dz*dz per half, IEEE == scalar.
            const v2f P_ = (v2f){px, px}, Q_ = (v2f){py, py}, R_ = (v2f){pz, pz};
            float m[PPT];
#pragma unroll
            for (int j = 0; j < NPAIR; ++j) {
                const v2f dx = X[j] - P_, dy = Y[j] - Q_, dz = Z[j] - R_;
                const v2f d = (dx * dx + dy * dy) + dz * dz;
                const float m0 = fminf(md[2 * j + 0], d.x);
                const float m1 = fminf(md[2 * j + 1], d.y);
                md[2 * j + 0] = m0;
                md[2 * j + 1] = m1;
                m[2 * j + 0] = m0;
                m[2 * j + 1] = m1;
            }
#pragma unroll
            for (int st = 1; st < PPT; st <<= 1)
#pragma unroll
                for (int i = 0; i < PPT; i += 2 * st)
                    m[i] = fmaxf(m[i], m[i + st]);
            const float best = m[0];

            // --- wave max (DPP) + first-lane tie-break via ballot
            const float wmax = wave_fmax_dpp(best);
            const unsigned long long mb = __ballot(best == wmax);
            const int ol = (int)__builtin_ctzll(mb);

            // --- owner: re-derive lowest i (descending overwrite), publish
            const int pb = s & 1;
            if (lane == ol) {
                int bi = 0;
#pragma unroll
                for (int i = PPT - 1; i >= 0; --i)
                    if (md[i] == wmax) bi = i;
                const int j = bi >> 1;
                const int h = bi & 1;
                const float wx = h ? X[j].y : X[j].x;
                const float wy = h ? Y[j].y : Y[j].x;
                const float wz = h ? Z[j].y : Z[j].x;
                pub[pb][wid] = make_float4(wmax, wx, wy, wz);
            }
            __syncthreads();               // the ONLY per-step barrier

            // --- serial scan of 8 wave winners (strict > -> lowest wid ties)
            float4 v0 = pub[pb][0];
            float gmax = v0.x;
            px = v0.y; py = v0.z; pz = v0.w;
#pragma unroll
            for (int w = 1; w < 8; ++w) {
                const float4 u = pub[pb][w];
                const bool g = u.x > gmax;
                gmax = g ? u.x : gmax;
                px = g ? u.y : px;
                py = g ? u.z : py;
                pz = g ? u.w : pz;
            }
            if (t == 0) {
                cent[3 * s + 0] = px;
                cent[3 * s + 1] = py;
                cent[3 * s + 2] = pz;
            }

            // ---- chunk publish: barrier, copy, barrier (vmcnt drain), release
            if ((s & (CHUNK_STEP - 1)) == (CHUNK_STEP - 1)) {
                __syncthreads();           // t0's cent[3s] visible to copiers
                const int base = 3 * (s - (CHUNK_STEP - 1));
                if (t < 3 * CHUNK_STEP) cb[base + t] = cent[base + t];
                __syncthreads();           // drains copiers' stores (vmcnt0)
                if (t == 0)
                    __hip_atomic_store(&progress[b], (unsigned)(s + 1),
                                       __ATOMIC_RELEASE, __HIP_MEMORY_SCOPE_AGENT);
            }
        }
    } else {
        // ======================= KNN workers ===============================
        const int w = blk - B;
        const int b = w & 7;               // same XCD as FPS block b (%8 rr)
        const int wchunk = w >> 3;         // 0..30
        const int waveid = wchunk * 8 + (t >> 6);   // 0..247 within batch
        const float* xb = xyz + (size_t)b * N * 3;

        unsigned seen = 0;                 // register-cached progress[b]
        for (int s = waveid; s < S; s += WVB) {
            while (seen <= (unsigned)s) {
                seen = __hip_atomic_load(&progress[b], __ATOMIC_ACQUIRE,
                                         __HIP_MEMORY_SCOPE_AGENT);
                if (seen <= (unsigned)s) __builtin_amdgcn_s_sleep(64);
            }

            const float* c = centers + (size_t)(b * S + s) * 3;
            const float cx = c[0], cy = c[1], cz = c[2];

            unsigned long long P = ~0ULL;   // lanes 0..31: sorted top-32 (asc)
            unsigned long long tau = ~0ULL;

            for (int i = 0; i < N / 64; ++i) {
                const int p = (i << 6) + lane;
                const float* q = xb + 3 * p;
                const float d = sqdist3(q[0], q[1], q[2], cx, cy, cz);
                const unsigned long long cand =
                    ((unsigned long long)__float_as_uint(d) << 32) | (unsigned)p;
                bool alive = cand < tau;
                unsigned long long mask = __ballot(alive);
                while (mask) {
                    const int src = __builtin_ctzll(mask);
                    const unsigned long long bc = __shfl(cand, src);
                    unsigned long long up = __shfl_up(P, 1);
                    if (lane == 0) up = bc;
                    const bool gt = P > bc;
                    const unsigned long long shifted = (up > bc) ? up : bc;
                    P = gt ? shifted : P;
                    tau = __shfl(P, 31);
                    if (lane == src) alive = false;
                    alive = alive && (cand < tau);
                    mask = __ballot(alive);
                }
            }

            if (lane < K) {
                const unsigned nidx = (unsigned)P;
                const float* q = xb + 3 * nidx;
                float* o = out + ((size_t)(b * S + s) * K + lane) * 3;
                o[0] = q[0] - cx;
                o[1] = q[1] - cy;
                o[2] = q[2] - cz;
            }
        }
    }
}

extern "C" void kernel_launch(void* const* d_in, const int* in_sizes, int n_in,
                              void* d_out, int out_size, void* d_ws, size_t ws_size,
                              hipStream_t stream) {
    const float* xyz = (const float*)d_in[0];
    float* out = (float*)d_out;                         // neighborhood [B,S,K,3]
    float* centers = out + (size_t)B * S * K * 3;       // centers [B,S,3]
    unsigned* progress = (unsigned*)d_ws;               // [B] centers-ready count

    // d_ws is poisoned 0xAA before every timed launch -> must zero progress
    hipMemsetAsync(d_ws, 0, B * sizeof(unsigned), stream);

    fused_kernel<<<B + WPB * B, TPB, 0, stream>>>(xyz, out, centers, progress);
}

// Round 12
// 2824.861 us; speedup vs baseline: 1.3224x; 1.3224x over previous
//
#include <hip/hip_runtime.h>

#define B 8
#define N 8192
#define S 2048
#define K 32
#define TPB 512           // all blocks: 8 waves
#define PPT (N / TPB)     // 16 contiguous points per FPS thread
#define CHUNK_STEP 128    // FPS publish cadence
#define WPB 31            // worker blocks per batch
#define WVB (WPB * 8)     // 248 KNN waves per batch (stride)

// Exact (no-FMA, left-to-right) squared distance to match numpy fp32:
// ((dx*dx + dy*dy) + dz*dz). FPS argmax is a chaotic recurrence; any ulp
// difference diverges the center sequence. Verified absmax==0 (R1-R11).
// NOTE: no ext_vector types anywhere -- R10/R11 proved any v2f use in this
// kernel wrecks register allocation (+SGPR churn, scalarized min/max).
__device__ __forceinline__ float sqdist3(float ax, float ay, float az,
                                         float bx, float by, float bz) {
    float dx = ax - bx, dy = ay - by, dz = az - bz;
    return __fadd_rn(__fadd_rn(__fmul_rn(dx, dx), __fmul_rn(dy, dy)),
                     __fmul_rn(dz, dz));
}

template <int CTRL>
__device__ __forceinline__ float dpp_fmax(float v) {
    const int iv = __float_as_int(v);
    const int sh = __builtin_amdgcn_update_dpp(iv, iv, CTRL, 0xF, 0xF, false);
    return fmaxf(v, __int_as_float(sh));
}
__device__ __forceinline__ float wave_fmax_dpp(float v) {
    v = dpp_fmax<0x111>(v);  // row_shr:1
    v = dpp_fmax<0x112>(v);  // row_shr:2
    v = dpp_fmax<0x114>(v);  // row_shr:4
    v = dpp_fmax<0x118>(v);  // row_shr:8
    v = dpp_fmax<0x142>(v);  // row_bcast:15
    v = dpp_fmax<0x143>(v);  // row_bcast:31 -> lane 63 = wave max
    return __int_as_float(__builtin_amdgcn_readlane(__float_as_int(v), 63));
}

// ---------------------------------------------------------------------------
// Fused producer-consumer (R9-verified structure), 256 blocks x 512 threads.
//  - blocks 0..7: FPS producer (R9 scalar hot loop verbatim). R12's single
//    change: the post-barrier scan of the 8 wave-winners is LANE-PARALLEL --
//    one ds_read_b128 per thread (pub[lane&7], slots replicated 8x/wave) +
//    DPP max + ballot/ctz + 3 readlanes, replacing 8 serial broadcast
//    ds_read_b128 per thread (64 wave-level LDS instrs/CU/step -> 16).
//    Tie-break exact: lowest lane with max == lowest wid == lowest gid.
//  - blocks 8..255: strided KNN workers (R9-verified, untouched): wave w
//    handles centers w, w+248, ...; waits on progress[b] > s (agent-ACQUIRE
//    + s_sleep); FPS publishes every 128 steps w/ agent-RELEASE after a
//    store-draining barrier (cross-XCD safe per G16).
// Invariants: FPS (max dist, min gid); KNN (d, idx) lexicographic == stable
// top_k. absmax must stay 0.
// ---------------------------------------------------------------------------
__global__ __launch_bounds__(TPB, 2) void fused_kernel(
    const float* __restrict__ xyz, float* __restrict__ out,
    float* __restrict__ centers, unsigned* __restrict__ progress) {
    const int blk = blockIdx.x;
    const int t = threadIdx.x;
    const int lane = t & 63;

    if (blk < B) {
        // =================== FPS producer (R9 structure) ===================
        const int b = blk;
        const float* xb = xyz + (size_t)b * N * 3;
        float* cb = centers + (size_t)b * S * 3;
        const int wid = t >> 6;

        float x[PPT], y[PPT], z[PPT], md[PPT];
        {
            float raw[3 * PPT];
            const float4* src = (const float4*)(xb + 3 * PPT * t);
#pragma unroll
            for (int i = 0; i < 3 * PPT / 4; ++i) {
                const float4 v = src[i];
                raw[4 * i + 0] = v.x; raw[4 * i + 1] = v.y;
                raw[4 * i + 2] = v.z; raw[4 * i + 3] = v.w;
            }
#pragma unroll
            for (int i = 0; i < PPT; ++i) {
                x[i] = raw[3 * i + 0];
                y[i] = raw[3 * i + 1];
                z[i] = raw[3 * i + 2];
                md[i] = INFINITY;
            }
        }

        __shared__ float4 pub[2][8];       // per-wave {wmax,x,y,z}, dbuf
        __shared__ float cent[S * 3];      // centers staged in LDS (24 KB)

        float px = xb[0], py = xb[1], pz = xb[2];   // step 0: point 0
        if (t == 0) { cent[0] = px; cent[1] = py; cent[2] = pz; }

        for (int s = 1; s < S; ++s) {
            // local update; tree max (no index tracking in hot path)
            float m[PPT];
#pragma unroll
            for (int i = 0; i < PPT; ++i) {
                const float d = sqdist3(x[i], y[i], z[i], px, py, pz);
                m[i] = fminf(md[i], d);
                md[i] = m[i];
            }
#pragma unroll
            for (int st = 1; st < PPT; st <<= 1)
#pragma unroll
                for (int i = 0; i < PPT; i += 2 * st)
                    m[i] = fmaxf(m[i], m[i + st]);
            const float best = m[0];

            // wave max (DPP) + first-lane tie-break via ballot
            const float wmax = wave_fmax_dpp(best);
            const unsigned long long mb = __ballot(best == wmax);
            const int ol = (int)__builtin_ctzll(mb);

            // owner: re-derive lowest i (descending overwrite), publish
            const int pb = s & 1;
            if (lane == ol) {
                int bi = 0;
#pragma unroll
                for (int i = PPT - 1; i >= 0; --i)
                    if (md[i] == wmax) bi = i;
                pub[pb][wid] = make_float4(wmax, x[bi], y[bi], z[bi]);
            }
            __syncthreads();               // the ONLY per-step barrier

            // --- R12: lane-parallel scan. lane L reads slot L&7 (one b128;
            //     8 slots replicated 8x across the wave). DPP max over 64
            //     lanes == max over 8 slots; lowest lane with max == lowest
            //     wid (lanes 0-7 cover wids 0-7) == lowest gid on ties.
            const float4 v = pub[pb][lane & 7];
            const float gmax = wave_fmax_dpp(v.x);
            const unsigned long long gb = __ballot(v.x == gmax);
            const int gl = (int)__builtin_ctzll(gb);
            px = __int_as_float(__builtin_amdgcn_readlane(__float_as_int(v.y), gl));
            py = __int_as_float(__builtin_amdgcn_readlane(__float_as_int(v.z), gl));
            pz = __int_as_float(__builtin_amdgcn_readlane(__float_as_int(v.w), gl));

            if (t == 0) {
                cent[3 * s + 0] = px;
                cent[3 * s + 1] = py;
                cent[3 * s + 2] = pz;
            }

            // ---- chunk publish: barrier, copy, barrier (vmcnt drain), release
            if ((s & (CHUNK_STEP - 1)) == (CHUNK_STEP - 1)) {
                __syncthreads();           // t0's cent[3s] visible to copiers
                const int base = 3 * (s - (CHUNK_STEP - 1));
                if (t < 3 * CHUNK_STEP) cb[base + t] = cent[base + t];
                __syncthreads();           // drains copiers' stores (vmcnt0)
                if (t == 0)
                    __hip_atomic_store(&progress[b], (unsigned)(s + 1),
                                       __ATOMIC_RELEASE, __HIP_MEMORY_SCOPE_AGENT);
            }
        }
    } else {
        // ======================= KNN workers ===============================
        const int w = blk - B;
        const int b = w & 7;               // same XCD as FPS block b (%8 rr)
        const int wchunk = w >> 3;         // 0..30
        const int waveid = wchunk * 8 + (t >> 6);   // 0..247 within batch
        const float* xb = xyz + (size_t)b * N * 3;

        unsigned seen = 0;                 // register-cached progress[b]
        for (int s = waveid; s < S; s += WVB) {
            while (seen <= (unsigned)s) {
                seen = __hip_atomic_load(&progress[b], __ATOMIC_ACQUIRE,
                                         __HIP_MEMORY_SCOPE_AGENT);
                if (seen <= (unsigned)s) __builtin_amdgcn_s_sleep(64);
            }

            const float* c = centers + (size_t)(b * S + s) * 3;
            const float cx = c[0], cy = c[1], cz = c[2];

            unsigned long long P = ~0ULL;   // lanes 0..31: sorted top-32 (asc)
            unsigned long long tau = ~0ULL;

            for (int i = 0; i < N / 64; ++i) {
                const int p = (i << 6) + lane;
                const float* q = xb + 3 * p;
                const float d = sqdist3(q[0], q[1], q[2], cx, cy, cz);
                const unsigned long long cand =
                    ((unsigned long long)__float_as_uint(d) << 32) | (unsigned)p;
                bool alive = cand < tau;
                unsigned long long mask = __ballot(alive);
                while (mask) {
                    const int src = __builtin_ctzll(mask);
                    const unsigned long long bc = __shfl(cand, src);
                    unsigned long long up = __shfl_up(P, 1);
                    if (lane == 0) up = bc;
                    const bool gt = P > bc;
                    const unsigned long long shifted = (up > bc) ? up : bc;
                    P = gt ? shifted : P;
                    tau = __shfl(P, 31);
                    if (lane == src) alive = false;
                    alive = alive && (cand < tau);
                    mask = __ballot(alive);
                }
            }

            if (lane < K) {
                const unsigned nidx = (unsigned)P;
                const float* q = xb + 3 * nidx;
                float* o = out + ((size_t)(b * S + s) * K + lane) * 3;
                o[0] = q[0] - cx;
                o[1] = q[1] - cy;
                o[2] = q[2] - cz;
            }
        }
    }
}

extern "C" void kernel_launch(void* const* d_in, const int* in_sizes, int n_in,
                              void* d_out, int out_size, void* d_ws, size_t ws_size,
                              hipStream_t stream) {
    const float* xyz = (const float*)d_in[0];
    float* out = (float*)d_out;                         // neighborhood [B,S,K,3]
    float* centers = out + (size_t)B * S * K * 3;       // centers [B,S,3]
    unsigned* progress = (unsigned*)d_ws;               // [B] centers-ready count

    // d_ws is poisoned 0xAA before every timed launch -> must zero progress
    hipMemsetAsync(d_ws, 0, B * sizeof(unsigned), stream);

    fused_kernel<<<B + WPB * B, TPB, 0, stream>>>(xyz, out, centers, progress);
}

// Round 13
// 2332.401 us; speedup vs baseline: 1.6017x; 1.2111x over previous
//
#include <hip/hip_runtime.h>

#define B 8
#define N 8192
#define S 2048
#define K 32
#define TPB 512           // all blocks: 8 waves
#define PPT (N / TPB)     // 16 contiguous points per FPS thread
#define CHUNK_STEP 128    // FPS publish cadence
#define WPB 31            // worker blocks per batch
#define WVB (WPB * 8)     // 248 KNN waves per batch (stride)

// Exact (no-FMA, left-to-right) squared distance to match numpy fp32:
// ((dx*dx + dy*dy) + dz*dz). FPS argmax is a chaotic recurrence; any ulp
// difference diverges the center sequence. Verified absmax==0 (R1-R12).
// Sensitivity ledger (do NOT "improve" these):
//  - no ext_vector/v2f anywhere (R10/R11: regalloc churn, -15..-60%)
//  - serial 8-slot scan, not lane-parallel (R12: dependent-chain, -20%)
//  - one block per batch (R6: cross-CU spin, -8x)
//  - 512 threads / 8 waves (R2/R7: other widths slower)
__device__ __forceinline__ float sqdist3(float ax, float ay, float az,
                                         float bx, float by, float bz) {
    float dx = ax - bx, dy = ay - by, dz = az - bz;
    return __fadd_rn(__fadd_rn(__fmul_rn(dx, dx), __fmul_rn(dy, dy)),
                     __fmul_rn(dz, dz));
}

template <int CTRL>
__device__ __forceinline__ float dpp_fmax(float v) {
    const int iv = __float_as_int(v);
    const int sh = __builtin_amdgcn_update_dpp(iv, iv, CTRL, 0xF, 0xF, false);
    return fmaxf(v, __int_as_float(sh));
}
__device__ __forceinline__ float wave_fmax_dpp(float v) {
    v = dpp_fmax<0x111>(v);  // row_shr:1
    v = dpp_fmax<0x112>(v);  // row_shr:2
    v = dpp_fmax<0x114>(v);  // row_shr:4
    v = dpp_fmax<0x118>(v);  // row_shr:8
    v = dpp_fmax<0x142>(v);  // row_bcast:15
    v = dpp_fmax<0x143>(v);  // row_bcast:31 -> lane 63 = wave max
    return __int_as_float(__builtin_amdgcn_readlane(__float_as_int(v), 63));
}

// ---------------------------------------------------------------------------
// Fused producer-consumer (R9 == verified best, 2315 us), 256 blocks x 512.
//  - blocks 0..7: FPS producer. 16 contiguous points/thread in registers;
//    one barrier/step; zero global ops in the step body; per-wave winner
//    published as one float4 {wmax,x,y,z}; serial scan of the 8 slots
//    (independent broadcast b128 loads -> single lgkmcnt wait + cndmask
//    tree). Every 128 steps: barrier, copy chunk LDS->global, barrier
//    (drains vmcnt), t0 agent-RELEASE store of progress[b] (L2 writeback,
//    cross-XCD safe per G16).
//  - blocks 8..255: 31 worker blocks/batch, STRIDED center assignment:
//    wave w handles centers w, w+248, ...; per-center wait on
//    progress[b] > s (agent-ACQUIRE broadcast load + s_sleep backoff).
//    Tail after final publish: <=1 center/wave (~15 us).
// Invariants: FPS picks (max dist, then lowest gid); KNN keeps (d, idx)
// lexicographic == stable top_k. absmax must stay 0.
// ---------------------------------------------------------------------------
__global__ __launch_bounds__(TPB, 2) void fused_kernel(
    const float* __restrict__ xyz, float* __restrict__ out,
    float* __restrict__ centers, unsigned* __restrict__ progress) {
    const int blk = blockIdx.x;
    const int t = threadIdx.x;
    const int lane = t & 63;

    if (blk < B) {
        // =================== FPS producer ===================
        const int b = blk;
        const float* xb = xyz + (size_t)b * N * 3;
        float* cb = centers + (size_t)b * S * 3;
        const int wid = t >> 6;

        float x[PPT], y[PPT], z[PPT], md[PPT];
        {
            float raw[3 * PPT];
            const float4* src = (const float4*)(xb + 3 * PPT * t);
#pragma unroll
            for (int i = 0; i < 3 * PPT / 4; ++i) {
                const float4 v = src[i];
                raw[4 * i + 0] = v.x; raw[4 * i + 1] = v.y;
                raw[4 * i + 2] = v.z; raw[4 * i + 3] = v.w;
            }
#pragma unroll
            for (int i = 0; i < PPT; ++i) {
                x[i] = raw[3 * i + 0];
                y[i] = raw[3 * i + 1];
                z[i] = raw[3 * i + 2];
                md[i] = INFINITY;
            }
        }

        __shared__ float4 pub[2][8];       // per-wave {wmax,x,y,z}, dbuf
        __shared__ float cent[S * 3];      // centers staged in LDS (24 KB)

        float px = xb[0], py = xb[1], pz = xb[2];   // step 0: point 0
        if (t == 0) { cent[0] = px; cent[1] = py; cent[2] = pz; }

        for (int s = 1; s < S; ++s) {
            // local update; tree max (no index tracking in hot path)
            float m[PPT];
#pragma unroll
            for (int i = 0; i < PPT; ++i) {
                const float d = sqdist3(x[i], y[i], z[i], px, py, pz);
                m[i] = fminf(md[i], d);
                md[i] = m[i];
            }
#pragma unroll
            for (int st = 1; st < PPT; st <<= 1)
#pragma unroll
                for (int i = 0; i < PPT; i += 2 * st)
                    m[i] = fmaxf(m[i], m[i + st]);
            const float best = m[0];

            // wave max (DPP) + first-lane tie-break via ballot
            const float wmax = wave_fmax_dpp(best);
            const unsigned long long mb = __ballot(best == wmax);
            const int ol = (int)__builtin_ctzll(mb);

            // owner: re-derive lowest i (descending overwrite), publish
            const int pb = s & 1;
            if (lane == ol) {
                int bi = 0;
#pragma unroll
                for (int i = PPT - 1; i >= 0; --i)
                    if (md[i] == wmax) bi = i;
                pub[pb][wid] = make_float4(wmax, x[bi], y[bi], z[bi]);
            }
            __syncthreads();               // the ONLY per-step barrier

            // serial scan of 8 wave winners (strict > -> lowest wid on ties)
            float4 v0 = pub[pb][0];
            float gmax = v0.x;
            px = v0.y; py = v0.z; pz = v0.w;
#pragma unroll
            for (int w = 1; w < 8; ++w) {
                const float4 u = pub[pb][w];
                const bool g = u.x > gmax;
                gmax = g ? u.x : gmax;
                px = g ? u.y : px;
                py = g ? u.z : py;
                pz = g ? u.w : pz;
            }
            if (t == 0) {
                cent[3 * s + 0] = px;
                cent[3 * s + 1] = py;
                cent[3 * s + 2] = pz;
            }

            // ---- chunk publish: barrier, copy, barrier (vmcnt drain), release
            if ((s & (CHUNK_STEP - 1)) == (CHUNK_STEP - 1)) {
                __syncthreads();           // t0's cent[3s] visible to copiers
                const int base = 3 * (s - (CHUNK_STEP - 1));
                if (t < 3 * CHUNK_STEP) cb[base + t] = cent[base + t];
                __syncthreads();           // drains copiers' stores (vmcnt0)
                if (t == 0)
                    __hip_atomic_store(&progress[b], (unsigned)(s + 1),
                                       __ATOMIC_RELEASE, __HIP_MEMORY_SCOPE_AGENT);
            }
        }
    } else {
        // ======================= KNN workers ===============================
        const int w = blk - B;
        const int b = w & 7;               // same XCD as FPS block b (%8 rr)
        const int wchunk = w >> 3;         // 0..30
        const int waveid = wchunk * 8 + (t >> 6);   // 0..247 within batch
        const float* xb = xyz + (size_t)b * N * 3;

        unsigned seen = 0;                 // register-cached progress[b]
        for (int s = waveid; s < S; s += WVB) {
            while (seen <= (unsigned)s) {
                seen = __hip_atomic_load(&progress[b], __ATOMIC_ACQUIRE,
                                         __HIP_MEMORY_SCOPE_AGENT);
                if (seen <= (unsigned)s) __builtin_amdgcn_s_sleep(64);
            }

            const float* c = centers + (size_t)(b * S + s) * 3;
            const float cx = c[0], cy = c[1], cz = c[2];

            unsigned long long P = ~0ULL;   // lanes 0..31: sorted top-32 (asc)
            unsigned long long tau = ~0ULL;

            for (int i = 0; i < N / 64; ++i) {
                const int p = (i << 6) + lane;
                const float* q = xb + 3 * p;
                const float d = sqdist3(q[0], q[1], q[2], cx, cy, cz);
                const unsigned long long cand =
                    ((unsigned long long)__float_as_uint(d) << 32) | (unsigned)p;
                bool alive = cand < tau;
                unsigned long long mask = __ballot(alive);
                while (mask) {
                    const int src = __builtin_ctzll(mask);
                    const unsigned long long bc = __shfl(cand, src);
                    unsigned long long up = __shfl_up(P, 1);
                    if (lane == 0) up = bc;
                    const bool gt = P > bc;
                    const unsigned long long shifted = (up > bc) ? up : bc;
                    P = gt ? shifted : P;
                    tau = __shfl(P, 31);
                    if (lane == src) alive = false;
                    alive = alive && (cand < tau);
                    mask = __ballot(alive);
                }
            }

            if (lane < K) {
                const unsigned nidx = (unsigned)P;
                const float* q = xb + 3 * nidx;
                float* o = out + ((size_t)(b * S + s) * K + lane) * 3;
                o[0] = q[0] - cx;
                o[1] = q[1] - cy;
                o[2] = q[2] - cz;
            }
        }
    }
}

extern "C" void kernel_launch(void* const* d_in, const int* in_sizes, int n_in,
                              void* d_out, int out_size, void* d_ws, size_t ws_size,
                              hipStream_t stream) {
    const float* xyz = (const float*)d_in[0];
    float* out = (float*)d_out;                         // neighborhood [B,S,K,3]
    float* centers = out + (size_t)B * S * K * 3;       // centers [B,S,3]
    unsigned* progress = (unsigned*)d_ws;               // [B] centers-ready count

    // d_ws is poisoned 0xAA before every timed launch -> must zero progress
    hipMemsetAsync(d_ws, 0, B * sizeof(unsigned), stream);

    fused_kernel<<<B + WPB * B, TPB, 0, stream>>>(xyz, out, centers, progress);
}